// Round 7
// baseline (500.777 us; speedup 1.0000x reference)
//
#include <hip/hip_runtime.h>
#include <hip/hip_bf16.h>

// Problem constants (shapes fixed by the reference)
#define DIM 256          // feature dim (D == H == 256)
#define KDIM 512         // fused K = D(agg) + D(root)

typedef unsigned short ushort_t;
typedef __attribute__((ext_vector_type(8))) short short8;   // 8 x bf16 (4 VGPRs) MFMA A/B frag
typedef __attribute__((ext_vector_type(4))) float f32x4;    // MFMA C/D frag

__device__ __forceinline__ float bf2f(ushort_t u) {
    union { unsigned int i; float f; } c; c.i = ((unsigned int)u) << 16; return c.f;
}
__device__ __forceinline__ ushort_t f2bf(float f) {
    unsigned int x = __float_as_uint(f);
    unsigned int r = (x + 0x7fffu + ((x >> 16) & 1u)) >> 16;
    return (ushort_t)r;
}

// async global->LDS, 16B/lane; LDS dest = wave-uniform base + lane*16
__device__ __forceinline__ void gload_lds16(const ushort_t* g, ushort_t* l) {
    __builtin_amdgcn_global_load_lds(
        (const __attribute__((address_space(1))) unsigned int*)g,
        (__attribute__((address_space(3))) unsigned int*)l, 16, 0, 0);
}

// inline edge_index dtype probe: int64 storage => odd int32 words all zero
__device__ __forceinline__ bool ei_is64(const int* __restrict__ ei) {
    int any = 0;
#pragma unroll
    for (int i = 0; i < 64; ++i) any |= ei[2 * i + 1];
    return any == 0;
}

// ---------------- prep: convert x->bf16 | pack 3 weight sets | histogram ----------------
// grid partition: [0,cb) convert, [cb,cb+pb) pack, [cb+pb,cb+pb+hb) hist

__global__ __launch_bounds__(256)
void prep_kernel(const float* __restrict__ x, ushort_t* __restrict__ xb, int n4, int cb,
                 const float* __restrict__ W0r, const float* __restrict__ W0o,
                 const float* __restrict__ W1r, const float* __restrict__ W1o,
                 const float* __restrict__ W2r, const float* __restrict__ W2o,
                 ushort_t* __restrict__ Wt, int pb,
                 const int* __restrict__ ei, int* __restrict__ deg, int E, int Nn) {
    int bid = blockIdx.x;
    int t = threadIdx.x;
    if (bid < cb) {
        int i = bid * 256 + t;
        if (i < n4) {
            const float4 v = *(const float4*)(x + (size_t)i * 4);
            ushort4 o;
            o.x = f2bf(v.x); o.y = f2bf(v.y); o.z = f2bf(v.z); o.w = f2bf(v.w);
            *(ushort4*)(xb + (size_t)i * 4) = o;
        }
    } else if (bid < cb + pb) {
        int id = (bid - cb) * 256 + t;            // over 3*131072
        int layer = id >> 17;
        int rem = id & 131071;
        int n = rem >> 9;       // /512
        int k = rem & 511;
        const float* Wr = (layer == 0) ? W0r : (layer == 1) ? W1r : W2r;
        const float* Wo = (layer == 0) ? W0o : (layer == 1) ? W1o : W2o;
        float v = (k < DIM) ? Wr[k * DIM + n] : Wo[(k - DIM) * DIM + n];
        Wt[id] = f2bf(v);
    } else {
        int e = (bid - cb - pb) * 256 + t;
        if (e < E) {
            bool is64 = ei_is64(ei);
            int d = is64 ? ei[2 * (E + e)] : ei[E + e];   // dst node
            d = (d < 0) ? 0 : (d >= Nn ? Nn - 1 : d);
            atomicAdd(&deg[d], 1);
        }
    }
}

// ---------------- scan: deg -> row_ptr/cursor (2 kernels) ----------------

__global__ __launch_bounds__(256)
void scan1_kernel(const int* __restrict__ deg, int* __restrict__ partials, int Nn) {
    __shared__ int red[256];
    int t = threadIdx.x;
    int base = blockIdx.x * 1024 + t * 4;
    int s = 0;
    if (base + 3 < Nn) {
        const int4 v = *(const int4*)(deg + base);
        s = v.x + v.y + v.z + v.w;
    } else {
        for (int i = 0; i < 4; ++i) if (base + i < Nn) s += deg[base + i];
    }
    red[t] = s;
    __syncthreads();
    for (int off = 128; off > 0; off >>= 1) {
        if (t < off) red[t] += red[t + off];
        __syncthreads();
    }
    if (t == 0) partials[blockIdx.x] = red[0];
}

__global__ __launch_bounds__(256)
void scan3_kernel(const int* __restrict__ deg, const int* __restrict__ partials,
                  int* __restrict__ row_ptr, int* __restrict__ cursor, int Nn, int E) {
    __shared__ int sdata[256];
    int t = threadIdx.x;
    // inline exclusive prefix of block partials (<= 49 L2-hot loads, redundant per thread)
    int pref = 0;
    for (int i = 0; i < blockIdx.x; ++i) pref += partials[i];
    int base = blockIdx.x * 1024 + t * 4;
    int d0 = 0, d1 = 0, d2 = 0, d3 = 0;
    if (base + 3 < Nn) {
        const int4 v = *(const int4*)(deg + base);
        d0 = v.x; d1 = v.y; d2 = v.z; d3 = v.w;
    } else {
        if (base + 0 < Nn) d0 = deg[base + 0];
        if (base + 1 < Nn) d1 = deg[base + 1];
        if (base + 2 < Nn) d2 = deg[base + 2];
        if (base + 3 < Nn) d3 = deg[base + 3];
    }
    int tsum = d0 + d1 + d2 + d3;
    sdata[t] = tsum;
    __syncthreads();
    for (int off = 1; off < 256; off <<= 1) {
        int u = (t >= off) ? sdata[t - off] : 0;
        __syncthreads();
        sdata[t] += u;
        __syncthreads();
    }
    int p0 = sdata[t] - tsum + pref;
    int p1 = p0 + d0, p2 = p1 + d1, p3 = p2 + d2;
    if (base + 3 < Nn) {
        *(int4*)(row_ptr + base) = make_int4(p0, p1, p2, p3);
        *(int4*)(cursor  + base) = make_int4(p0, p1, p2, p3);
    } else {
        if (base + 0 < Nn) { row_ptr[base + 0] = p0; cursor[base + 0] = p0; }
        if (base + 1 < Nn) { row_ptr[base + 1] = p1; cursor[base + 1] = p1; }
        if (base + 2 < Nn) { row_ptr[base + 2] = p2; cursor[base + 2] = p2; }
        if (base + 3 < Nn) { row_ptr[base + 3] = p3; cursor[base + 3] = p3; }
    }
    if (blockIdx.x == 0 && t == 0) row_ptr[Nn] = E;
}

__global__ void fill_kernel(const int* __restrict__ ei, int* __restrict__ cursor,
                            int* __restrict__ srcs, int E, int Nn) {
    int e = blockIdx.x * blockDim.x + threadIdx.x;
    if (e < E) {
        bool is64 = ei_is64(ei);
        int d = is64 ? ei[2 * (E + e)] : ei[E + e];
        int s = is64 ? ei[2 * e]       : ei[e];
        d = (d < 0) ? 0 : (d >= Nn ? Nn - 1 : d);
        s = (s < 0) ? 0 : (s >= Nn ? Nn - 1 : s);
        int p = atomicAdd(&cursor[d], 1);
        srcs[p] = s;
    }
}

// ---------------- aggregation: one wave per node; edge loop unrolled x8 ----------------

__global__ __launch_bounds__(256)
void agg_kernel(const ushort_t* __restrict__ xin, const int* __restrict__ row_ptr,
                const int* __restrict__ srcs, ushort_t* __restrict__ aggout, int Nn) {
    int gid = blockIdx.x * blockDim.x + threadIdx.x;
    int node = gid >> 6;
    int lane = gid & 63;
    if (node >= Nn) return;
    int beg = row_ptr[node], end = row_ptr[node + 1];
    float a0 = 0.f, a1 = 0.f, a2 = 0.f, a3 = 0.f;
    const int off = lane * 4;
    int e = beg;
    for (; e + 7 < end; e += 8) {
        int s0 = srcs[e],     s1 = srcs[e + 1], s2 = srcs[e + 2], s3 = srcs[e + 3];
        int s4 = srcs[e + 4], s5 = srcs[e + 5], s6 = srcs[e + 6], s7 = srcs[e + 7];
        const ushort4 v0 = *(const ushort4*)(xin + (size_t)s0 * DIM + off);
        const ushort4 v1 = *(const ushort4*)(xin + (size_t)s1 * DIM + off);
        const ushort4 v2 = *(const ushort4*)(xin + (size_t)s2 * DIM + off);
        const ushort4 v3 = *(const ushort4*)(xin + (size_t)s3 * DIM + off);
        const ushort4 v4 = *(const ushort4*)(xin + (size_t)s4 * DIM + off);
        const ushort4 v5 = *(const ushort4*)(xin + (size_t)s5 * DIM + off);
        const ushort4 v6 = *(const ushort4*)(xin + (size_t)s6 * DIM + off);
        const ushort4 v7 = *(const ushort4*)(xin + (size_t)s7 * DIM + off);
        a0 += bf2f(v0.x); a1 += bf2f(v0.y); a2 += bf2f(v0.z); a3 += bf2f(v0.w);
        a0 += bf2f(v1.x); a1 += bf2f(v1.y); a2 += bf2f(v1.z); a3 += bf2f(v1.w);
        a0 += bf2f(v2.x); a1 += bf2f(v2.y); a2 += bf2f(v2.z); a3 += bf2f(v2.w);
        a0 += bf2f(v3.x); a1 += bf2f(v3.y); a2 += bf2f(v3.z); a3 += bf2f(v3.w);
        a0 += bf2f(v4.x); a1 += bf2f(v4.y); a2 += bf2f(v4.z); a3 += bf2f(v4.w);
        a0 += bf2f(v5.x); a1 += bf2f(v5.y); a2 += bf2f(v5.z); a3 += bf2f(v5.w);
        a0 += bf2f(v6.x); a1 += bf2f(v6.y); a2 += bf2f(v6.z); a3 += bf2f(v6.w);
        a0 += bf2f(v7.x); a1 += bf2f(v7.y); a2 += bf2f(v7.z); a3 += bf2f(v7.w);
    }
    for (; e < end; ++e) {
        int s = srcs[e];
        const ushort4 v = *(const ushort4*)(xin + (size_t)s * DIM + off);
        a0 += bf2f(v.x); a1 += bf2f(v.y); a2 += bf2f(v.z); a3 += bf2f(v.w);
    }
    ushort4 o;
    o.x = f2bf(a0); o.y = f2bf(a1); o.z = f2bf(a2); o.w = f2bf(a3);
    *(ushort4*)(aggout + (size_t)node * DIM + off) = o;
}

// ---------------- fused GEMM: out = elu([agg|root] @ W + bias) ----------------
// BM=64, BN=256 (full H in one block => A rows read ONCE; B 0.5 MB stays L2-hot).
// 4 waves side-by-side in N: wave w covers cols [w*64, w*64+64), 4x4 MFMA 16x16x32 frags.
// LDS: As 64x32 (4 KB), Bs 256x32 (16 KB); 16 K-steps of BK=32, staged via global_load_lds.

template <bool OUT_F32>
__global__ __launch_bounds__(256)
void gemm_fused_kernel(const ushort_t* __restrict__ Aagg, const ushort_t* __restrict__ Ax,
                       const ushort_t* __restrict__ Wt, const float* __restrict__ bias,
                       void* __restrict__ outp, int M) {
    __shared__ __align__(16) ushort_t As[64 * 32];
    __shared__ __align__(16) ushort_t Bs[256 * 32];
    const int t = threadIdx.x;
    const int w = t >> 6, l = t & 63;
    const int bm = blockIdx.x;

    f32x4 acc[4][4] = {};

    // staging: per gload a wave covers 16 rows (4 lanes/row, 16B chunks)
    const int sub = l >> 2;                 // row-within-16
    const int kq  = l & 3;                  // 16B chunk within 64B row
    const int arow = w * 16 + sub;          // A row 0..63
    int ga = bm * 64 + arow; if (ga > M - 1) ga = M - 1;
    ushort_t* AsW = &As[(w * 16) * 32];     // + lane*16B implicit
    const int brow = w * 64 + sub;          // B rows: w*64 + j*16 + sub
    ushort_t* BsW = &Bs[(w * 64) * 32];

    const int mrow = l & 15;                // A frag row (+ mi*16)
    const int nrow = w * 64 + (l & 15);     // B frag row (+ ni*16)
    const int koff = (l >> 4) * 8;

    for (int ks = 0; ks < 16; ++ks) {
        const int k0 = ks * 32;
        const ushort_t* Ab = (k0 < DIM) ? (Aagg + k0) : (Ax + (k0 - DIM));
        gload_lds16(Ab + (size_t)ga * DIM + kq * 8, AsW);
        const ushort_t* Wb = Wt + k0 + kq * 8;
#pragma unroll
        for (int j = 0; j < 4; ++j)
            gload_lds16(Wb + (size_t)(brow + j * 16) * KDIM, BsW + j * 16 * 32);
        __syncthreads();   // drains vmcnt(0): staging complete

        short8 af[4], bfv[4];
#pragma unroll
        for (int i = 0; i < 4; ++i) {
            af[i]  = *(const short8*)&As[(mrow + i * 16) * 32 + koff];
            bfv[i] = *(const short8*)&Bs[(nrow + i * 16) * 32 + koff];
        }
#pragma unroll
        for (int mi = 0; mi < 4; ++mi)
#pragma unroll
            for (int ni = 0; ni < 4; ++ni)
                acc[mi][ni] = __builtin_amdgcn_mfma_f32_16x16x32_bf16(
                    af[mi], bfv[ni], acc[mi][ni], 0, 0, 0);
        __syncthreads();
    }

    // epilogue: bias + ELU; C/D layout col=lane&15, row=(lane>>4)*4+reg
    const int col0 = w * 64 + (l & 15);
    const int rb   = bm * 64 + ((l >> 4) << 2);
    float bv[4];
#pragma unroll
    for (int ni = 0; ni < 4; ++ni) bv[ni] = bias[col0 + ni * 16];
#pragma unroll
    for (int mi = 0; mi < 4; ++mi) {
#pragma unroll
        for (int r = 0; r < 4; ++r) {
            int node = rb + mi * 16 + r;
            if (node < M) {
#pragma unroll
                for (int ni = 0; ni < 4; ++ni) {
                    float v = acc[mi][ni][r] + bv[ni];
                    v = v > 0.f ? v : (__expf(v) - 1.f);
                    if (OUT_F32)
                        ((float*)outp)[(size_t)node * DIM + col0 + ni * 16] = v;
                    else
                        ((ushort_t*)outp)[(size_t)node * DIM + col0 + ni * 16] = f2bf(v);
                }
            }
        }
    }
}

// ---------------- launcher ----------------
// fp32 in / fp32 out per the reference dtypes. Internals in bf16.
// d_out hosts xb and h1 (both dead before layer-3 fp32 overwrite).

extern "C" void kernel_launch(void* const* d_in, const int* in_sizes, int n_in,
                              void* d_out, int out_size, void* d_ws, size_t ws_size,
                              hipStream_t stream) {
    const float* x  = (const float*)d_in[0];
    const int*   ei = (const int*)d_in[1];
    const float* Wrel[3] = { (const float*)d_in[2], (const float*)d_in[5], (const float*)d_in[8] };
    const float* bias[3] = { (const float*)d_in[3], (const float*)d_in[6], (const float*)d_in[9] };
    const float* Wroot[3]= { (const float*)d_in[4], (const float*)d_in[7], (const float*)d_in[10] };

    const int Nn = in_sizes[0] / DIM;      // 50000
    const int E  = in_sizes[1] / 2;        // 800000

    char* ws = (char*)d_ws;
    size_t off = 0;
    auto alloc = [&](size_t bytes) {
        char* p = ws + off;
        off = (off + bytes + 1023) & ~(size_t)1023;
        return p;
    };
    int* deg      = (int*)alloc((size_t)Nn * 4);
    int* row_ptr  = (int*)alloc((size_t)(Nn + 1) * 4);
    int* cursor   = (int*)alloc((size_t)Nn * 4);
    int* partials = (int*)alloc(64 * 4);
    int* srcs     = (int*)alloc((size_t)E * 4);
    ushort_t* Wt  = (ushort_t*)alloc((size_t)3 * DIM * KDIM * 2);   // 3 layers contiguous
    ushort_t* aggbuf = (ushort_t*)alloc((size_t)Nn * DIM * 2);
    ushort_t* h2     = (ushort_t*)alloc((size_t)Nn * DIM * 2);
    (void)ws_size; (void)n_in; (void)out_size;

    ushort_t* xb = (ushort_t*)d_out;            // bf16 x copy (d_out lower half)
    ushort_t* h1 = xb + (size_t)Nn * DIM;       // bf16 hidden-1 (d_out upper half)

    // 1) prep (convert | pack | hist) + scan + fill
    const int n4 = Nn * DIM / 4;
    const int cb = (n4 + 255) / 256;                     // 12500
    const int pb = (3 * DIM * KDIM + 255) / 256;         // 1536
    const int hb = (E + 255) / 256;                      // 3125
    const int nb = (Nn + 1023) / 1024;                   // 49 scan blocks

    hipMemsetAsync(deg, 0, (size_t)Nn * 4, stream);
    prep_kernel<<<cb + pb + hb, 256, 0, stream>>>(
        x, xb, n4, cb,
        Wrel[0], Wroot[0], Wrel[1], Wroot[1], Wrel[2], Wroot[2], Wt, pb,
        ei, deg, E, Nn);
    scan1_kernel<<<nb, 256, 0, stream>>>(deg, partials, Nn);
    scan3_kernel<<<nb, 256, 0, stream>>>(deg, partials, row_ptr, cursor, Nn, E);
    fill_kernel<<<hb, 256, 0, stream>>>(ei, cursor, srcs, E, Nn);

    // 2) three GraphConv layers
    const int aggBlocks = (Nn * 64 + 255) / 256;          // one wave per node
    const int gBlocks   = (Nn + 63) / 64;                 // 782

    agg_kernel<<<aggBlocks, 256, 0, stream>>>(xb, row_ptr, srcs, aggbuf, Nn);
    gemm_fused_kernel<false><<<gBlocks, 256, 0, stream>>>(aggbuf, xb, Wt, bias[0], h1, Nn);

    agg_kernel<<<aggBlocks, 256, 0, stream>>>(h1, row_ptr, srcs, aggbuf, Nn);
    gemm_fused_kernel<false><<<gBlocks, 256, 0, stream>>>(aggbuf, h1, Wt + DIM * KDIM, bias[1], h2, Nn);

    agg_kernel<<<aggBlocks, 256, 0, stream>>>(h2, row_ptr, srcs, aggbuf, Nn);
    gemm_fused_kernel<true><<<gBlocks, 256, 0, stream>>>(aggbuf, h2, Wt + 2 * DIM * KDIM, bias[2], d_out, Nn);
}

// Round 8
// 478.659 us; speedup vs baseline: 1.0462x; 1.0462x over previous
//
#include <hip/hip_runtime.h>
#include <hip/hip_bf16.h>

// Problem constants (shapes fixed by the reference)
#define DIM 256          // feature dim (D == H == 256)
#define KDIM 512         // fused K = D(agg) + D(root)

typedef unsigned short ushort_t;
typedef __attribute__((ext_vector_type(8))) short short8;   // 8 x bf16 (4 VGPRs) MFMA A/B frag
typedef __attribute__((ext_vector_type(4))) float f32x4;    // MFMA C/D frag

__device__ __forceinline__ float bf2f(ushort_t u) {
    union { unsigned int i; float f; } c; c.i = ((unsigned int)u) << 16; return c.f;
}
__device__ __forceinline__ ushort_t f2bf(float f) {
    unsigned int x = __float_as_uint(f);
    unsigned int r = (x + 0x7fffu + ((x >> 16) & 1u)) >> 16;
    return (ushort_t)r;
}

// async global->LDS, 16B/lane; LDS dest = wave-uniform base + lane*16
__device__ __forceinline__ void gload_lds16(const ushort_t* g, ushort_t* l) {
    __builtin_amdgcn_global_load_lds(
        (const __attribute__((address_space(1))) unsigned int*)g,
        (__attribute__((address_space(3))) unsigned int*)l, 16, 0, 0);
}

// ---------------- edge_index dtype probe (ONCE; flag read is scalar thereafter) ----------------
__global__ void detect_kernel(const int* __restrict__ ei, int* __restrict__ flag) {
    __shared__ int any;
    if (threadIdx.x == 0) any = 0;
    __syncthreads();
    if (ei[2 * threadIdx.x + 1] != 0) atomicOr(&any, 1);
    __syncthreads();
    if (threadIdx.x == 0) *flag = (any == 0) ? 1 : 0;   // 1 => int64 layout
}

// ---------------- prep: convert x->bf16 | pack 3 weight sets | histogram ----------------
// grid partition: [0,cb) convert, [cb,cb+pb) pack, [cb+pb,cb+pb+hb) hist

__global__ __launch_bounds__(256)
void prep_kernel(const float* __restrict__ x, ushort_t* __restrict__ xb, int n4, int cb,
                 const float* __restrict__ W0r, const float* __restrict__ W0o,
                 const float* __restrict__ W1r, const float* __restrict__ W1o,
                 const float* __restrict__ W2r, const float* __restrict__ W2o,
                 ushort_t* __restrict__ Wt, int pb,
                 const int* __restrict__ ei, const int* __restrict__ flag,
                 int* __restrict__ deg, int E, int Nn) {
    int bid = blockIdx.x;
    int t = threadIdx.x;
    if (bid < cb) {
        int i = bid * 256 + t;
        if (i < n4) {
            const float4 v = *(const float4*)(x + (size_t)i * 4);
            ushort4 o;
            o.x = f2bf(v.x); o.y = f2bf(v.y); o.z = f2bf(v.z); o.w = f2bf(v.w);
            *(ushort4*)(xb + (size_t)i * 4) = o;
        }
    } else if (bid < cb + pb) {
        int id = (bid - cb) * 256 + t;            // over 3*131072
        int layer = id >> 17;
        int rem = id & 131071;
        int n = rem >> 9;       // /512
        int k = rem & 511;
        const float* Wr = (layer == 0) ? W0r : (layer == 1) ? W1r : W2r;
        const float* Wo = (layer == 0) ? W0o : (layer == 1) ? W1o : W2o;
        float v = (k < DIM) ? Wr[k * DIM + n] : Wo[(k - DIM) * DIM + n];
        Wt[id] = f2bf(v);
    } else {
        int e = (bid - cb - pb) * 256 + t;
        if (e < E) {
            int is64 = *flag;                       // wave-uniform scalar load
            int d = is64 ? ei[2 * (E + e)] : ei[E + e];   // dst node
            d = (d < 0) ? 0 : (d >= Nn ? Nn - 1 : d);
            atomicAdd(&deg[d], 1);
        }
    }
}

// ---------------- scan: deg -> row_ptr/cursor (2 kernels) ----------------

__global__ __launch_bounds__(256)
void scan1_kernel(const int* __restrict__ deg, int* __restrict__ partials, int Nn) {
    __shared__ int red[256];
    int t = threadIdx.x;
    int base = blockIdx.x * 1024 + t * 4;
    int s = 0;
    if (base + 3 < Nn) {
        const int4 v = *(const int4*)(deg + base);
        s = v.x + v.y + v.z + v.w;
    } else {
        for (int i = 0; i < 4; ++i) if (base + i < Nn) s += deg[base + i];
    }
    red[t] = s;
    __syncthreads();
    for (int off = 128; off > 0; off >>= 1) {
        if (t < off) red[t] += red[t + off];
        __syncthreads();
    }
    if (t == 0) partials[blockIdx.x] = red[0];
}

__global__ __launch_bounds__(256)
void scan3_kernel(const int* __restrict__ deg, const int* __restrict__ partials,
                  int* __restrict__ row_ptr, int* __restrict__ cursor, int Nn, int E) {
    __shared__ int sdata[256];
    int t = threadIdx.x;
    int pref = 0;
    for (int i = 0; i < blockIdx.x; ++i) pref += partials[i];   // <=49 L2-hot loads
    int base = blockIdx.x * 1024 + t * 4;
    int d0 = 0, d1 = 0, d2 = 0, d3 = 0;
    if (base + 3 < Nn) {
        const int4 v = *(const int4*)(deg + base);
        d0 = v.x; d1 = v.y; d2 = v.z; d3 = v.w;
    } else {
        if (base + 0 < Nn) d0 = deg[base + 0];
        if (base + 1 < Nn) d1 = deg[base + 1];
        if (base + 2 < Nn) d2 = deg[base + 2];
        if (base + 3 < Nn) d3 = deg[base + 3];
    }
    int tsum = d0 + d1 + d2 + d3;
    sdata[t] = tsum;
    __syncthreads();
    for (int off = 1; off < 256; off <<= 1) {
        int u = (t >= off) ? sdata[t - off] : 0;
        __syncthreads();
        sdata[t] += u;
        __syncthreads();
    }
    int p0 = sdata[t] - tsum + pref;
    int p1 = p0 + d0, p2 = p1 + d1, p3 = p2 + d2;
    if (base + 3 < Nn) {
        *(int4*)(row_ptr + base) = make_int4(p0, p1, p2, p3);
        *(int4*)(cursor  + base) = make_int4(p0, p1, p2, p3);
    } else {
        if (base + 0 < Nn) { row_ptr[base + 0] = p0; cursor[base + 0] = p0; }
        if (base + 1 < Nn) { row_ptr[base + 1] = p1; cursor[base + 1] = p1; }
        if (base + 2 < Nn) { row_ptr[base + 2] = p2; cursor[base + 2] = p2; }
        if (base + 3 < Nn) { row_ptr[base + 3] = p3; cursor[base + 3] = p3; }
    }
    if (blockIdx.x == 0 && t == 0) row_ptr[Nn] = E;
}

__global__ void fill_kernel(const int* __restrict__ ei, const int* __restrict__ flag,
                            int* __restrict__ cursor, int* __restrict__ srcs, int E, int Nn) {
    int e = blockIdx.x * blockDim.x + threadIdx.x;
    if (e < E) {
        int is64 = *flag;                           // wave-uniform scalar load
        int d = is64 ? ei[2 * (E + e)] : ei[E + e];
        int s = is64 ? ei[2 * e]       : ei[e];
        d = (d < 0) ? 0 : (d >= Nn ? Nn - 1 : d);
        s = (s < 0) ? 0 : (s >= Nn ? Nn - 1 : s);
        int p = atomicAdd(&cursor[d], 1);
        srcs[p] = s;
    }
}

// ---------------- aggregation: one wave per node; edge loop unrolled x4 ----------------

__global__ __launch_bounds__(256)
void agg_kernel(const ushort_t* __restrict__ xin, const int* __restrict__ row_ptr,
                const int* __restrict__ srcs, ushort_t* __restrict__ aggout, int Nn) {
    int gid = blockIdx.x * blockDim.x + threadIdx.x;
    int node = gid >> 6;
    int lane = gid & 63;
    if (node >= Nn) return;
    int beg = row_ptr[node], end = row_ptr[node + 1];
    float a0 = 0.f, a1 = 0.f, a2 = 0.f, a3 = 0.f;
    const int off = lane * 4;
    int e = beg;
    for (; e + 3 < end; e += 4) {
        int s0 = srcs[e], s1 = srcs[e + 1], s2 = srcs[e + 2], s3 = srcs[e + 3];
        const ushort4 v0 = *(const ushort4*)(xin + (size_t)s0 * DIM + off);
        const ushort4 v1 = *(const ushort4*)(xin + (size_t)s1 * DIM + off);
        const ushort4 v2 = *(const ushort4*)(xin + (size_t)s2 * DIM + off);
        const ushort4 v3 = *(const ushort4*)(xin + (size_t)s3 * DIM + off);
        a0 += bf2f(v0.x); a1 += bf2f(v0.y); a2 += bf2f(v0.z); a3 += bf2f(v0.w);
        a0 += bf2f(v1.x); a1 += bf2f(v1.y); a2 += bf2f(v1.z); a3 += bf2f(v1.w);
        a0 += bf2f(v2.x); a1 += bf2f(v2.y); a2 += bf2f(v2.z); a3 += bf2f(v2.w);
        a0 += bf2f(v3.x); a1 += bf2f(v3.y); a2 += bf2f(v3.z); a3 += bf2f(v3.w);
    }
    for (; e < end; ++e) {
        int s = srcs[e];
        const ushort4 v = *(const ushort4*)(xin + (size_t)s * DIM + off);
        a0 += bf2f(v.x); a1 += bf2f(v.y); a2 += bf2f(v.z); a3 += bf2f(v.w);
    }
    ushort4 o;
    o.x = f2bf(a0); o.y = f2bf(a1); o.z = f2bf(a2); o.w = f2bf(a3);
    *(ushort4*)(aggout + (size_t)node * DIM + off) = o;
}

// ---------------- fused GEMM: out = elu([agg|root] @ W + bias) ----------------
// BM=64, BN=256 (full H in one block => A rows read ONCE; B 0.5 MB stays L2-hot).
// 4 waves side-by-side in N: wave w covers cols [w*64, w*64+64), 4x4 MFMA 16x16x32 frags.
// LDS: As 64x32 (4 KB), Bs 256x32 (16 KB); 16 K-steps of BK=32, staged via global_load_lds.

template <bool OUT_F32>
__global__ __launch_bounds__(256)
void gemm_fused_kernel(const ushort_t* __restrict__ Aagg, const ushort_t* __restrict__ Ax,
                       const ushort_t* __restrict__ Wt, const float* __restrict__ bias,
                       void* __restrict__ outp, int M) {
    __shared__ __align__(16) ushort_t As[64 * 32];
    __shared__ __align__(16) ushort_t Bs[256 * 32];
    const int t = threadIdx.x;
    const int w = t >> 6, l = t & 63;
    const int bm = blockIdx.x;

    f32x4 acc[4][4] = {};

    const int sub = l >> 2;                 // row-within-16
    const int kq  = l & 3;                  // 16B chunk within 64B row
    const int arow = w * 16 + sub;          // A row 0..63
    int ga = bm * 64 + arow; if (ga > M - 1) ga = M - 1;
    ushort_t* AsW = &As[(w * 16) * 32];     // + lane*16B implicit
    const int brow = w * 64 + sub;          // B rows: w*64 + j*16 + sub
    ushort_t* BsW = &Bs[(w * 64) * 32];

    const int mrow = l & 15;                // A frag row (+ mi*16)
    const int nrow = w * 64 + (l & 15);     // B frag row (+ ni*16)
    const int koff = (l >> 4) * 8;

    for (int ks = 0; ks < 16; ++ks) {
        const int k0 = ks * 32;
        const ushort_t* Ab = (k0 < DIM) ? (Aagg + k0) : (Ax + (k0 - DIM));
        gload_lds16(Ab + (size_t)ga * DIM + kq * 8, AsW);
        const ushort_t* Wb = Wt + k0 + kq * 8;
#pragma unroll
        for (int j = 0; j < 4; ++j)
            gload_lds16(Wb + (size_t)(brow + j * 16) * KDIM, BsW + j * 16 * 32);
        __syncthreads();   // drains vmcnt(0): staging complete

        short8 af[4], bfv[4];
#pragma unroll
        for (int i = 0; i < 4; ++i) {
            af[i]  = *(const short8*)&As[(mrow + i * 16) * 32 + koff];
            bfv[i] = *(const short8*)&Bs[(nrow + i * 16) * 32 + koff];
        }
#pragma unroll
        for (int mi = 0; mi < 4; ++mi)
#pragma unroll
            for (int ni = 0; ni < 4; ++ni)
                acc[mi][ni] = __builtin_amdgcn_mfma_f32_16x16x32_bf16(
                    af[mi], bfv[ni], acc[mi][ni], 0, 0, 0);
        __syncthreads();
    }

    // epilogue: bias + ELU; C/D layout col=lane&15, row=(lane>>4)*4+reg
    const int col0 = w * 64 + (l & 15);
    const int rb   = bm * 64 + ((l >> 4) << 2);
    float bv[4];
#pragma unroll
    for (int ni = 0; ni < 4; ++ni) bv[ni] = bias[col0 + ni * 16];
#pragma unroll
    for (int mi = 0; mi < 4; ++mi) {
#pragma unroll
        for (int r = 0; r < 4; ++r) {
            int node = rb + mi * 16 + r;
            if (node < M) {
#pragma unroll
                for (int ni = 0; ni < 4; ++ni) {
                    float v = acc[mi][ni][r] + bv[ni];
                    v = v > 0.f ? v : (__expf(v) - 1.f);
                    if (OUT_F32)
                        ((float*)outp)[(size_t)node * DIM + col0 + ni * 16] = v;
                    else
                        ((ushort_t*)outp)[(size_t)node * DIM + col0 + ni * 16] = f2bf(v);
                }
            }
        }
    }
}

// ---------------- launcher ----------------
// fp32 in / fp32 out per the reference dtypes. Internals in bf16.
// d_out hosts xb and h1 (both dead before layer-3 fp32 overwrite).

extern "C" void kernel_launch(void* const* d_in, const int* in_sizes, int n_in,
                              void* d_out, int out_size, void* d_ws, size_t ws_size,
                              hipStream_t stream) {
    const float* x  = (const float*)d_in[0];
    const int*   ei = (const int*)d_in[1];
    const float* Wrel[3] = { (const float*)d_in[2], (const float*)d_in[5], (const float*)d_in[8] };
    const float* bias[3] = { (const float*)d_in[3], (const float*)d_in[6], (const float*)d_in[9] };
    const float* Wroot[3]= { (const float*)d_in[4], (const float*)d_in[7], (const float*)d_in[10] };

    const int Nn = in_sizes[0] / DIM;      // 50000
    const int E  = in_sizes[1] / 2;        // 800000

    char* ws = (char*)d_ws;
    size_t off = 0;
    auto alloc = [&](size_t bytes) {
        char* p = ws + off;
        off = (off + bytes + 1023) & ~(size_t)1023;
        return p;
    };
    int* flag     = (int*)alloc(4);
    int* deg      = (int*)alloc((size_t)Nn * 4);
    int* row_ptr  = (int*)alloc((size_t)(Nn + 1) * 4);
    int* cursor   = (int*)alloc((size_t)Nn * 4);
    int* partials = (int*)alloc(64 * 4);
    int* srcs     = (int*)alloc((size_t)E * 4);
    ushort_t* Wt  = (ushort_t*)alloc((size_t)3 * DIM * KDIM * 2);   // 3 layers contiguous
    ushort_t* aggbuf = (ushort_t*)alloc((size_t)Nn * DIM * 2);
    ushort_t* h2     = (ushort_t*)alloc((size_t)Nn * DIM * 2);
    (void)ws_size; (void)n_in; (void)out_size;

    ushort_t* xb = (ushort_t*)d_out;            // bf16 x copy (d_out lower half)
    ushort_t* h1 = xb + (size_t)Nn * DIM;       // bf16 hidden-1 (d_out upper half)

    // 1) probe + prep (convert | pack | hist) + scan + fill
    const int n4 = Nn * DIM / 4;
    const int cb = (n4 + 255) / 256;                     // 12500
    const int pb = (3 * DIM * KDIM + 255) / 256;         // 1536
    const int hb = (E + 255) / 256;                      // 3125
    const int nb = (Nn + 1023) / 1024;                   // 49 scan blocks

    detect_kernel<<<1, 256, 0, stream>>>(ei, flag);
    hipMemsetAsync(deg, 0, (size_t)Nn * 4, stream);
    prep_kernel<<<cb + pb + hb, 256, 0, stream>>>(
        x, xb, n4, cb,
        Wrel[0], Wroot[0], Wrel[1], Wroot[1], Wrel[2], Wroot[2], Wt, pb,
        ei, flag, deg, E, Nn);
    scan1_kernel<<<nb, 256, 0, stream>>>(deg, partials, Nn);
    scan3_kernel<<<nb, 256, 0, stream>>>(deg, partials, row_ptr, cursor, Nn, E);
    fill_kernel<<<hb, 256, 0, stream>>>(ei, flag, cursor, srcs, E, Nn);

    // 2) three GraphConv layers
    const int aggBlocks = (Nn * 64 + 255) / 256;          // one wave per node
    const int gBlocks   = (Nn + 63) / 64;                 // 782

    agg_kernel<<<aggBlocks, 256, 0, stream>>>(xb, row_ptr, srcs, aggbuf, Nn);
    gemm_fused_kernel<false><<<gBlocks, 256, 0, stream>>>(aggbuf, xb, Wt, bias[0], h1, Nn);

    agg_kernel<<<aggBlocks, 256, 0, stream>>>(h1, row_ptr, srcs, aggbuf, Nn);
    gemm_fused_kernel<false><<<gBlocks, 256, 0, stream>>>(aggbuf, h1, Wt + DIM * KDIM, bias[1], h2, Nn);

    agg_kernel<<<aggBlocks, 256, 0, stream>>>(h2, row_ptr, srcs, aggbuf, Nn);
    gemm_fused_kernel<true><<<gBlocks, 256, 0, stream>>>(aggbuf, h2, Wt + 2 * DIM * KDIM, bias[2], d_out, Nn);
}

// Round 9
// 474.342 us; speedup vs baseline: 1.0557x; 1.0091x over previous
//
#include <hip/hip_runtime.h>
#include <hip/hip_bf16.h>

// Problem constants (shapes fixed by the reference)
#define DIM 256          // feature dim (D == H == 256)
#define KDIM 512         // fused K = D(agg) + D(root)

typedef unsigned short ushort_t;
typedef __attribute__((ext_vector_type(8))) short short8;   // 8 x bf16 (4 VGPRs) MFMA A/B frag
typedef __attribute__((ext_vector_type(4))) float f32x4;    // MFMA C/D frag

__device__ __forceinline__ float bf2f(ushort_t u) {
    union { unsigned int i; float f; } c; c.i = ((unsigned int)u) << 16; return c.f;
}
__device__ __forceinline__ ushort_t f2bf(float f) {
    unsigned int x = __float_as_uint(f);
    unsigned int r = (x + 0x7fffu + ((x >> 16) & 1u)) >> 16;
    return (ushort_t)r;
}

// async global->LDS, 16B/lane; LDS dest = wave-uniform base + lane*16
__device__ __forceinline__ void gload_lds16(const ushort_t* g, ushort_t* l) {
    __builtin_amdgcn_global_load_lds(
        (const __attribute__((address_space(1))) unsigned int*)g,
        (__attribute__((address_space(3))) unsigned int*)l, 16, 0, 0);
}

// ---------------- edge_index dtype probe (ONCE; flag read is scalar thereafter) ----------------
__global__ void detect_kernel(const int* __restrict__ ei, int* __restrict__ flag) {
    __shared__ int any;
    if (threadIdx.x == 0) any = 0;
    __syncthreads();
    if (ei[2 * threadIdx.x + 1] != 0) atomicOr(&any, 1);
    __syncthreads();
    if (threadIdx.x == 0) *flag = (any == 0) ? 1 : 0;   // 1 => int64 layout
}

// ---------------- prep: convert x->bf16 | pack 3 weight sets (frag tiles) | histogram ----------------
// B pack layout per layer: Bp[ks][nt][lane][h]  (16*16*64*8 halves = 256 KB)
//   n = nt*16 + (lane&15),  k = ks*32 + (lane>>4)*8 + h
// => wave B-frag (ks, nt) is ONE contiguous 1KB block, coalesced global->VGPR.

__global__ __launch_bounds__(256)
void prep_kernel(const float* __restrict__ x, ushort_t* __restrict__ xb, int n4, int cb,
                 const float* __restrict__ W0r, const float* __restrict__ W0o,
                 const float* __restrict__ W1r, const float* __restrict__ W1o,
                 const float* __restrict__ W2r, const float* __restrict__ W2o,
                 ushort_t* __restrict__ Wt, int pb,
                 const int* __restrict__ ei, const int* __restrict__ flag,
                 int* __restrict__ deg, int E, int Nn) {
    int bid = blockIdx.x;
    int t = threadIdx.x;
    if (bid < cb) {
        int i = bid * 256 + t;
        if (i < n4) {
            const float4 v = *(const float4*)(x + (size_t)i * 4);
            ushort4 o;
            o.x = f2bf(v.x); o.y = f2bf(v.y); o.z = f2bf(v.z); o.w = f2bf(v.w);
            *(ushort4*)(xb + (size_t)i * 4) = o;
        }
    } else if (bid < cb + pb) {
        int id = (bid - cb) * 256 + t;            // over 3*131072
        int layer = id >> 17;
        int rem = id & 131071;
        int ks   = rem >> 13;                     // 8192 per ks
        int nt   = (rem >> 9) & 15;
        int lane = (rem >> 3) & 63;
        int h    = rem & 7;
        int n = nt * 16 + (lane & 15);
        int k = ks * 32 + ((lane >> 4) << 3) + h;
        const float* Wr = (layer == 0) ? W0r : (layer == 1) ? W1r : W2r;
        const float* Wo = (layer == 0) ? W0o : (layer == 1) ? W1o : W2o;
        float v = (k < DIM) ? Wr[k * DIM + n] : Wo[(k - DIM) * DIM + n];
        Wt[id] = f2bf(v);
    } else {
        int e = (bid - cb - pb) * 256 + t;
        if (e < E) {
            int is64 = *flag;                       // wave-uniform scalar load
            int d = is64 ? ei[2 * (E + e)] : ei[E + e];   // dst node
            d = (d < 0) ? 0 : (d >= Nn ? Nn - 1 : d);
            atomicAdd(&deg[d], 1);
        }
    }
}

// ---------------- scan: deg -> row_ptr/cursor (2 kernels) ----------------

__global__ __launch_bounds__(256)
void scan1_kernel(const int* __restrict__ deg, int* __restrict__ partials, int Nn) {
    __shared__ int red[256];
    int t = threadIdx.x;
    int base = blockIdx.x * 1024 + t * 4;
    int s = 0;
    if (base + 3 < Nn) {
        const int4 v = *(const int4*)(deg + base);
        s = v.x + v.y + v.z + v.w;
    } else {
        for (int i = 0; i < 4; ++i) if (base + i < Nn) s += deg[base + i];
    }
    red[t] = s;
    __syncthreads();
    for (int off = 128; off > 0; off >>= 1) {
        if (t < off) red[t] += red[t + off];
        __syncthreads();
    }
    if (t == 0) partials[blockIdx.x] = red[0];
}

__global__ __launch_bounds__(256)
void scan3_kernel(const int* __restrict__ deg, const int* __restrict__ partials,
                  int* __restrict__ row_ptr, int* __restrict__ cursor, int Nn, int E) {
    __shared__ int sdata[256];
    int t = threadIdx.x;
    int pref = 0;
    for (int i = 0; i < blockIdx.x; ++i) pref += partials[i];   // <=49 L2-hot loads
    int base = blockIdx.x * 1024 + t * 4;
    int d0 = 0, d1 = 0, d2 = 0, d3 = 0;
    if (base + 3 < Nn) {
        const int4 v = *(const int4*)(deg + base);
        d0 = v.x; d1 = v.y; d2 = v.z; d3 = v.w;
    } else {
        if (base + 0 < Nn) d0 = deg[base + 0];
        if (base + 1 < Nn) d1 = deg[base + 1];
        if (base + 2 < Nn) d2 = deg[base + 2];
        if (base + 3 < Nn) d3 = deg[base + 3];
    }
    int tsum = d0 + d1 + d2 + d3;
    sdata[t] = tsum;
    __syncthreads();
    for (int off = 1; off < 256; off <<= 1) {
        int u = (t >= off) ? sdata[t - off] : 0;
        __syncthreads();
        sdata[t] += u;
        __syncthreads();
    }
    int p0 = sdata[t] - tsum + pref;
    int p1 = p0 + d0, p2 = p1 + d1, p3 = p2 + d2;
    if (base + 3 < Nn) {
        *(int4*)(row_ptr + base) = make_int4(p0, p1, p2, p3);
        *(int4*)(cursor  + base) = make_int4(p0, p1, p2, p3);
    } else {
        if (base + 0 < Nn) { row_ptr[base + 0] = p0; cursor[base + 0] = p0; }
        if (base + 1 < Nn) { row_ptr[base + 1] = p1; cursor[base + 1] = p1; }
        if (base + 2 < Nn) { row_ptr[base + 2] = p2; cursor[base + 2] = p2; }
        if (base + 3 < Nn) { row_ptr[base + 3] = p3; cursor[base + 3] = p3; }
    }
    if (blockIdx.x == 0 && t == 0) row_ptr[Nn] = E;
}

__global__ void fill_kernel(const int* __restrict__ ei, const int* __restrict__ flag,
                            int* __restrict__ cursor, int* __restrict__ srcs, int E, int Nn) {
    int e = blockIdx.x * blockDim.x + threadIdx.x;
    if (e < E) {
        int is64 = *flag;                           // wave-uniform scalar load
        int d = is64 ? ei[2 * (E + e)] : ei[E + e];
        int s = is64 ? ei[2 * e]       : ei[e];
        d = (d < 0) ? 0 : (d >= Nn ? Nn - 1 : d);
        s = (s < 0) ? 0 : (s >= Nn ? Nn - 1 : s);
        int p = atomicAdd(&cursor[d], 1);
        srcs[p] = s;
    }
}

// ---------------- aggregation: one wave per node; edge loop unrolled x4 ----------------

__global__ __launch_bounds__(256)
void agg_kernel(const ushort_t* __restrict__ xin, const int* __restrict__ row_ptr,
                const int* __restrict__ srcs, ushort_t* __restrict__ aggout, int Nn) {
    int gid = blockIdx.x * blockDim.x + threadIdx.x;
    int node = gid >> 6;
    int lane = gid & 63;
    if (node >= Nn) return;
    int beg = row_ptr[node], end = row_ptr[node + 1];
    float a0 = 0.f, a1 = 0.f, a2 = 0.f, a3 = 0.f;
    const int off = lane * 4;
    int e = beg;
    for (; e + 3 < end; e += 4) {
        int s0 = srcs[e], s1 = srcs[e + 1], s2 = srcs[e + 2], s3 = srcs[e + 3];
        const ushort4 v0 = *(const ushort4*)(xin + (size_t)s0 * DIM + off);
        const ushort4 v1 = *(const ushort4*)(xin + (size_t)s1 * DIM + off);
        const ushort4 v2 = *(const ushort4*)(xin + (size_t)s2 * DIM + off);
        const ushort4 v3 = *(const ushort4*)(xin + (size_t)s3 * DIM + off);
        a0 += bf2f(v0.x); a1 += bf2f(v0.y); a2 += bf2f(v0.z); a3 += bf2f(v0.w);
        a0 += bf2f(v1.x); a1 += bf2f(v1.y); a2 += bf2f(v1.z); a3 += bf2f(v1.w);
        a0 += bf2f(v2.x); a1 += bf2f(v2.y); a2 += bf2f(v2.z); a3 += bf2f(v2.w);
        a0 += bf2f(v3.x); a1 += bf2f(v3.y); a2 += bf2f(v3.z); a3 += bf2f(v3.w);
    }
    for (; e < end; ++e) {
        int s = srcs[e];
        const ushort4 v = *(const ushort4*)(xin + (size_t)s * DIM + off);
        a0 += bf2f(v.x); a1 += bf2f(v.y); a2 += bf2f(v.z); a3 += bf2f(v.w);
    }
    ushort4 o;
    o.x = f2bf(a0); o.y = f2bf(a1); o.z = f2bf(a2); o.w = f2bf(a3);
    *(ushort4*)(aggout + (size_t)node * DIM + off) = o;
}

// ---------------- fused GEMM: out = elu([agg|root] @ W + bias) — BARRIER-FREE K-loop ----------------
// BM=64, BN=256, 4 waves (wave w -> cols [w*64,w*64+64)), 4x4 MFMA 16x16x32 frags.
// A panel 64x512 staged into LDS ONCE (16 gload_lds16/wave, one __syncthreads).
// B read directly global->VGPR from frag-coalesced pack (1KB per frag, L2-hot). No K-loop barriers.
// LDS layout: As[ks][64][32] (16 tiles of 4KB, same staging/ds_read pattern as the m97-verified step).

template <bool OUT_F32>
__global__ __launch_bounds__(256)
void gemm_fused_kernel(const ushort_t* __restrict__ Aagg, const ushort_t* __restrict__ Ax,
                       const ushort_t* __restrict__ Bp, const float* __restrict__ bias,
                       void* __restrict__ outp, int M) {
    __shared__ __align__(16) ushort_t As[16 * 64 * 32];   // 64 KB
    const int t = threadIdx.x;
    const int w = t >> 6, l = t & 63;
    const int bm = blockIdx.x;

    // ---- stage full A panel (agg half -> tiles 0..7, root half -> tiles 8..15) ----
    const int sub = l >> 2;                 // row-within-16
    const int kq  = l & 3;                  // 16B chunk within 64B tile-row
    const int arow = w * 16 + sub;
    int ga = bm * 64 + arow; if (ga > M - 1) ga = M - 1;
    const ushort_t* aggRow = Aagg + (size_t)ga * DIM + kq * 8;
    const ushort_t* axRow  = Ax   + (size_t)ga * DIM + kq * 8;
    ushort_t* AsW = &As[(w * 16) * 32];     // + lane*16B implicit per tile
#pragma unroll
    for (int ks = 0; ks < 8; ++ks)
        gload_lds16(aggRow + ks * 32, AsW + ks * (64 * 32));
#pragma unroll
    for (int ks = 0; ks < 8; ++ks)
        gload_lds16(axRow + ks * 32, AsW + (8 + ks) * (64 * 32));
    __syncthreads();                        // only barrier in the kernel

    // ---- K-loop: direct B frag loads + LDS A frags + MFMA, no barriers ----
    f32x4 acc[4][4] = {};
    const int mrow = l & 15;
    const int koff = (l >> 4) * 8;
    const ushort_t* BpW = Bp + ((size_t)(w * 4) * 64 + l) * 8;   // nt0 = w*4
    // strides in halves: ks -> 16*64*8 = 8192, nt -> 64*8 = 512
#pragma unroll 4
    for (int ks = 0; ks < 16; ++ks) {
        short8 bf0 = *(const short8*)(BpW + ks * 8192 + 0 * 512);
        short8 bf1 = *(const short8*)(BpW + ks * 8192 + 1 * 512);
        short8 bf2 = *(const short8*)(BpW + ks * 8192 + 2 * 512);
        short8 bf3 = *(const short8*)(BpW + ks * 8192 + 3 * 512);
        short8 af[4];
#pragma unroll
        for (int mi = 0; mi < 4; ++mi)
            af[mi] = *(const short8*)&As[(ks * 64 + mrow + mi * 16) * 32 + koff];
#pragma unroll
        for (int mi = 0; mi < 4; ++mi) {
            acc[mi][0] = __builtin_amdgcn_mfma_f32_16x16x32_bf16(af[mi], bf0, acc[mi][0], 0, 0, 0);
            acc[mi][1] = __builtin_amdgcn_mfma_f32_16x16x32_bf16(af[mi], bf1, acc[mi][1], 0, 0, 0);
            acc[mi][2] = __builtin_amdgcn_mfma_f32_16x16x32_bf16(af[mi], bf2, acc[mi][2], 0, 0, 0);
            acc[mi][3] = __builtin_amdgcn_mfma_f32_16x16x32_bf16(af[mi], bf3, acc[mi][3], 0, 0, 0);
        }
    }

    // epilogue: bias + ELU; C/D layout col=lane&15, row=(lane>>4)*4+reg
    const int col0 = w * 64 + (l & 15);
    const int rb   = bm * 64 + ((l >> 4) << 2);
    float bv[4];
#pragma unroll
    for (int ni = 0; ni < 4; ++ni) bv[ni] = bias[col0 + ni * 16];
#pragma unroll
    for (int mi = 0; mi < 4; ++mi) {
#pragma unroll
        for (int r = 0; r < 4; ++r) {
            int node = rb + mi * 16 + r;
            if (node < M) {
#pragma unroll
                for (int ni = 0; ni < 4; ++ni) {
                    float v = acc[mi][ni][r] + bv[ni];
                    v = v > 0.f ? v : (__expf(v) - 1.f);
                    if (OUT_F32)
                        ((float*)outp)[(size_t)node * DIM + col0 + ni * 16] = v;
                    else
                        ((ushort_t*)outp)[(size_t)node * DIM + col0 + ni * 16] = f2bf(v);
                }
            }
        }
    }
}

// ---------------- launcher ----------------
// fp32 in / fp32 out per the reference dtypes. Internals in bf16.
// d_out hosts xb and h1 (both dead before layer-3 fp32 overwrite).

extern "C" void kernel_launch(void* const* d_in, const int* in_sizes, int n_in,
                              void* d_out, int out_size, void* d_ws, size_t ws_size,
                              hipStream_t stream) {
    const float* x  = (const float*)d_in[0];
    const int*   ei = (const int*)d_in[1];
    const float* Wrel[3] = { (const float*)d_in[2], (const float*)d_in[5], (const float*)d_in[8] };
    const float* bias[3] = { (const float*)d_in[3], (const float*)d_in[6], (const float*)d_in[9] };
    const float* Wroot[3]= { (const float*)d_in[4], (const float*)d_in[7], (const float*)d_in[10] };

    const int Nn = in_sizes[0] / DIM;      // 50000
    const int E  = in_sizes[1] / 2;        // 800000

    char* ws = (char*)d_ws;
    size_t off = 0;
    auto alloc = [&](size_t bytes) {
        char* p = ws + off;
        off = (off + bytes + 1023) & ~(size_t)1023;
        return p;
    };
    int* flag     = (int*)alloc(4);
    int* deg      = (int*)alloc((size_t)Nn * 4);
    int* row_ptr  = (int*)alloc((size_t)(Nn + 1) * 4);
    int* cursor   = (int*)alloc((size_t)Nn * 4);
    int* partials = (int*)alloc(64 * 4);
    int* srcs     = (int*)alloc((size_t)E * 4);
    ushort_t* Wt  = (ushort_t*)alloc((size_t)3 * DIM * KDIM * 2);   // 3 layers, frag-tile packed
    ushort_t* aggbuf = (ushort_t*)alloc((size_t)Nn * DIM * 2);
    ushort_t* h2     = (ushort_t*)alloc((size_t)Nn * DIM * 2);
    (void)ws_size; (void)n_in; (void)out_size;

    ushort_t* xb = (ushort_t*)d_out;            // bf16 x copy (d_out lower half)
    ushort_t* h1 = xb + (size_t)Nn * DIM;       // bf16 hidden-1 (d_out upper half)

    // 1) probe + prep (convert | pack | hist) + scan + fill
    const int n4 = Nn * DIM / 4;
    const int cb = (n4 + 255) / 256;                     // 12500
    const int pb = (3 * DIM * KDIM + 255) / 256;         // 1536
    const int hb = (E + 255) / 256;                      // 3125
    const int nb = (Nn + 1023) / 1024;                   // 49 scan blocks

    detect_kernel<<<1, 256, 0, stream>>>(ei, flag);
    hipMemsetAsync(deg, 0, (size_t)Nn * 4, stream);
    prep_kernel<<<cb + pb + hb, 256, 0, stream>>>(
        x, xb, n4, cb,
        Wrel[0], Wroot[0], Wrel[1], Wroot[1], Wrel[2], Wroot[2], Wt, pb,
        ei, flag, deg, E, Nn);
    scan1_kernel<<<nb, 256, 0, stream>>>(deg, partials, Nn);
    scan3_kernel<<<nb, 256, 0, stream>>>(deg, partials, row_ptr, cursor, Nn, E);
    fill_kernel<<<hb, 256, 0, stream>>>(ei, flag, cursor, srcs, E, Nn);

    // 2) three GraphConv layers
    const int aggBlocks = (Nn * 64 + 255) / 256;          // one wave per node
    const int gBlocks   = (Nn + 63) / 64;                 // 782

    agg_kernel<<<aggBlocks, 256, 0, stream>>>(xb, row_ptr, srcs, aggbuf, Nn);
    gemm_fused_kernel<false><<<gBlocks, 256, 0, stream>>>(aggbuf, xb, Wt, bias[0], h1, Nn);

    agg_kernel<<<aggBlocks, 256, 0, stream>>>(h1, row_ptr, srcs, aggbuf, Nn);
    gemm_fused_kernel<false><<<gBlocks, 256, 0, stream>>>(aggbuf, h1, Wt + DIM * KDIM, bias[1], h2, Nn);

    agg_kernel<<<aggBlocks, 256, 0, stream>>>(h2, row_ptr, srcs, aggbuf, Nn);
    gemm_fused_kernel<true><<<gBlocks, 256, 0, stream>>>(aggbuf, h2, Wt + 2 * DIM * KDIM, bias[2], d_out, Nn);
}